// Round 8
// baseline (1479.344 us; speedup 1.0000x reference)
//
#include <hip/hip_runtime.h>

// out[b, n, k, :] = features[b, topk_indices[b, n, k], :]
// B=32, N=4096, K=20, F=64, fp32.
//
// R8 DECOMPOSITION DIAGNOSTIC. Real kernel runs at 4.4 TB/s mixed
// (3.5 TB/s store-side) vs fill's 6.7 TB/s pure-write. Split the streams:
//   A: pure-write, exact same grid/iter/store shape (6 passes)
//   B: pure gather-read, sums sunk to out (12 passes)
//   C: real R1 gather (1 pass, last -> correct final output)
// asm "memory" barriers stop cross-pass DSE/CSE without touching caches
// (R4's __threadfence() polluted that measurement).

typedef float floatx4 __attribute__((ext_vector_type(4)));

constexpr int B = 32, N = 4096, K = 20, F = 64;
constexpr unsigned NK = (unsigned)N * K;                      // 81,920
constexpr unsigned VEC_PER_ROW = F / 4;                       // 16
constexpr unsigned TOTAL_ROWS = (unsigned)B * NK;             // 2,621,440
constexpr unsigned TOTAL_VEC = TOTAL_ROWS * VEC_PER_ROW;      // 41,943,040

constexpr unsigned BLOCK = 256;
constexpr unsigned GRID = 2048;
constexpr unsigned THREADS = GRID * BLOCK;                    // 524,288
constexpr unsigned ITERS = TOTAL_VEC / THREADS;               // exactly 80
static_assert(ITERS * THREADS == TOTAL_VEC, "exact tiling");

// ---- A: pure write stream, byte-identical store pattern to the real kernel
__global__ __launch_bounds__(BLOCK) void wr_only_kernel(
    float* __restrict__ out, int passes)
{
    const unsigned tid0 = blockIdx.x * BLOCK + threadIdx.x;
    floatx4* __restrict__ outv = reinterpret_cast<floatx4*>(out);
    for (int p = 0; p < passes; ++p) {
        floatx4 val = {(float)p, (float)(p + 1), (float)(p + 2), (float)(p + 3)};
        unsigned i = tid0;
#pragma unroll 1
        for (unsigned j = 0; j < ITERS; ++j, i += THREADS)
            outv[i] = val;
        asm volatile("" ::: "memory");   // block cross-pass dead-store elim
    }
}

// ---- B: pure gather-read stream, identical read pattern, tiny sink writes
__global__ __launch_bounds__(BLOCK) void rd_only_kernel(
    const int* __restrict__ idx, const float* __restrict__ feat,
    float* __restrict__ sink, int passes)
{
    const unsigned tid0 = blockIdx.x * BLOCK + threadIdx.x;
    const floatx4* __restrict__ featv = reinterpret_cast<const floatx4*>(feat);
    floatx4 acc = {0.f, 0.f, 0.f, 0.f};
    for (int p = 0; p < passes; ++p) {
        unsigned i = tid0;
#pragma unroll 1
        for (unsigned j = 0; j < ITERS; ++j, i += THREADS) {
            unsigned row = i >> 4;
            unsigned v   = i & 15u;
            unsigned b   = row / NK;
            int id       = idx[row];
            acc += featv[(b * (unsigned)N + (unsigned)id) * VEC_PER_ROW + v];
        }
        asm volatile("" ::: "memory");   // force re-load next pass (no CSE)
    }
    sink[tid0] = acc.x + acc.y + acc.z + acc.w;  // keep loads live (2 MB, overwritten by C)
}

// ---- C: the real gather (R1 body), runs last -> correct output
__global__ __launch_bounds__(BLOCK) void gather_rows_kernel(
    const int* __restrict__ idx, const float* __restrict__ feat,
    float* __restrict__ out)
{
    unsigned i = blockIdx.x * BLOCK + threadIdx.x;
    const floatx4* __restrict__ featv = reinterpret_cast<const floatx4*>(feat);
    floatx4* __restrict__ outv = reinterpret_cast<floatx4*>(out);
#pragma unroll 1
    for (unsigned j = 0; j < ITERS; ++j, i += THREADS) {
        unsigned row = i >> 4;
        unsigned v   = i & 15u;
        unsigned b   = row / NK;
        int id       = idx[row];
        outv[i] = featv[(b * (unsigned)N + (unsigned)id) * VEC_PER_ROW + v];
    }
}

extern "C" void kernel_launch(void* const* d_in, const int* in_sizes, int n_in,
                              void* d_out, int out_size, void* d_ws, size_t ws_size,
                              hipStream_t stream) {
    const int*   idx  = (const int*)d_in[0];    // topk_indices [B,N,K] int32
    const float* feat = (const float*)d_in[1];  // features [B,N,F] fp32
    float*       out  = (float*)d_out;          // [B,N,K,F] fp32

    wr_only_kernel<<<GRID, BLOCK, 0, stream>>>(out, 6);            // ~600+ us
    rd_only_kernel<<<GRID, BLOCK, 0, stream>>>(idx, feat, out, 12);// ~600-2000 us
    gather_rows_kernel<<<GRID, BLOCK, 0, stream>>>(idx, feat, out);// correct output
}

// Round 9
// 376.538 us; speedup vs baseline: 3.9288x; 3.9288x over previous
//
#include <hip/hip_runtime.h>

// out[b, n, k, :] = features[b, topk_indices[b, n, k], :]
// B=32, N=4096, K=20, F=64, fp32.
//
// R8 decomposition: rd-only 62.5us/pass, wr-only ~90us/pass, mixed 187us --
// mixed is 1.23x the SERIAL SUM of the split streams. Instruction-level
// schedule variants (nt/unroll/pipeline/XCD) all land at 187 -> the cost is
// fine-grained R/W mixing at the memory system, not wave scheduling.
// R9: block-level phase bursts. Each chunk: all 256 threads gather 16 float4
// into registers (64KB/block read burst), __syncthreads, then store them
// (64KB write burst). Macro-bursts replace 32B-granularity mixing.

constexpr int B = 32, N = 4096, K = 20, F = 64;
constexpr unsigned NK = (unsigned)N * K;                      // 81,920
constexpr unsigned VEC_PER_ROW = F / 4;                       // 16
constexpr unsigned TOTAL_ROWS = (unsigned)B * NK;             // 2,621,440
constexpr unsigned TOTAL_VEC = TOTAL_ROWS * VEC_PER_ROW;      // 41,943,040

constexpr unsigned BLOCK = 256;
constexpr unsigned GRID = 2048;
constexpr unsigned THREADS = GRID * BLOCK;                    // 524,288
constexpr unsigned ITERS = TOTAL_VEC / THREADS;               // exactly 80
constexpr unsigned CHUNK = 16;                                // float4 staged/thread
constexpr unsigned NCHUNK = ITERS / CHUNK;                    // 5
static_assert(NCHUNK * CHUNK == ITERS, "exact chunking");

__global__ __launch_bounds__(BLOCK) void gather_rows_kernel(
    const int* __restrict__ idx,      // [B, N, K]
    const float* __restrict__ feat,   // [B, N, F]
    float* __restrict__ out)          // [B, N, K, F]
{
    const unsigned tid0 = blockIdx.x * BLOCK + threadIdx.x;
    const float4* __restrict__ featv = reinterpret_cast<const float4*>(feat);
    float4* __restrict__ outv = reinterpret_cast<float4*>(out);

    for (unsigned c = 0; c < NCHUNK; ++c) {
        float4 vals[CHUNK];
        // ---- read burst: 16 gathered float4 -> registers (64KB per block)
#pragma unroll
        for (unsigned u = 0; u < CHUNK; ++u) {
            unsigned i   = tid0 + (c * CHUNK + u) * THREADS;
            unsigned row = i >> 4;
            unsigned v   = i & 15u;
            unsigned b   = row / NK;
            int id       = idx[row];
            vals[u] = featv[(b * (unsigned)N + (unsigned)id) * VEC_PER_ROW + v];
        }
        __syncthreads();                 // align all 8 waves: end read phase
        // ---- write burst: 16 coalesced float4 stores (64KB per block)
#pragma unroll
        for (unsigned u = 0; u < CHUNK; ++u) {
            outv[tid0 + (c * CHUNK + u) * THREADS] = vals[u];
        }
        __syncthreads();                 // end write phase before next reads
    }
}

extern "C" void kernel_launch(void* const* d_in, const int* in_sizes, int n_in,
                              void* d_out, int out_size, void* d_ws, size_t ws_size,
                              hipStream_t stream) {
    const int*   idx  = (const int*)d_in[0];    // topk_indices [B,N,K] int32
    const float* feat = (const float*)d_in[1];  // features [B,N,F] fp32
    float*       out  = (float*)d_out;          // [B,N,K,F] fp32

    gather_rows_kernel<<<GRID, BLOCK, 0, stream>>>(idx, feat, out);
}

// Round 10
// 205.014 us; speedup vs baseline: 7.2158x; 1.8366x over previous
//
#include <hip/hip_runtime.h>

// out[b, n, k, :] = features[b, topk_indices[b, n, k], :]
// B=32, N=4096, K=20, F=64, fp32.
//
// Ledger: naive=187, nt=234, unroll4(compiler)=208, XCD-affine=186,
// 1-deep pipeline=190, barrier-burst16=376. rd-only=62.5us, wr-only~90us.
// R10: the one untested cell -- explicit 8-deep load batch then store batch,
// NO barriers, full unroll. Forces: 8 loads in flight, stores drain on
// counted vmcnt(7..0) while next batch's loads can issue. Wave-granularity
// 8KB read-run / 8KB write-run instead of per-instruction L/S alternation.
// ~48 VGPR -> full 32-wave/CU occupancy preserved.

constexpr int B = 32, N = 4096, K = 20, F = 64;
constexpr unsigned NK = (unsigned)N * K;                      // 81,920
constexpr unsigned VEC_PER_ROW = F / 4;                       // 16
constexpr unsigned TOTAL_ROWS = (unsigned)B * NK;             // 2,621,440
constexpr unsigned TOTAL_VEC = TOTAL_ROWS * VEC_PER_ROW;      // 41,943,040

constexpr unsigned BLOCK = 256;
constexpr unsigned GRID = 2048;
constexpr unsigned THREADS = GRID * BLOCK;                    // 524,288
constexpr unsigned ITERS = TOTAL_VEC / THREADS;               // exactly 80
constexpr unsigned DEPTH = 8;                                 // loads batched per thread
constexpr unsigned NBATCH = ITERS / DEPTH;                    // 10
static_assert(NBATCH * DEPTH == ITERS, "exact batching");

__global__ __launch_bounds__(BLOCK) void gather_rows_kernel(
    const int* __restrict__ idx,      // [B, N, K]
    const float* __restrict__ feat,   // [B, N, F]
    float* __restrict__ out)          // [B, N, K, F]
{
    const unsigned tid0 = blockIdx.x * BLOCK + threadIdx.x;
    const float4* __restrict__ featv = reinterpret_cast<const float4*>(feat);
    float4* __restrict__ outv = reinterpret_cast<float4*>(out);

#pragma unroll 1
    for (unsigned c = 0; c < NBATCH; ++c) {
        float4 vals[DEPTH];
        // 8 independent gather chains issued back-to-back (all static idx)
#pragma unroll
        for (unsigned u = 0; u < DEPTH; ++u) {
            unsigned i   = tid0 + (c * DEPTH + u) * THREADS;
            unsigned row = i >> 4;
            unsigned v   = i & 15u;
            unsigned b   = row / NK;
            int id       = idx[row];
            vals[u] = featv[(b * (unsigned)N + (unsigned)id) * VEC_PER_ROW + v];
        }
        // 8 coalesced stores: drain on counted vmcnt as loads return
#pragma unroll
        for (unsigned u = 0; u < DEPTH; ++u) {
            outv[tid0 + (c * DEPTH + u) * THREADS] = vals[u];
        }
    }
}

extern "C" void kernel_launch(void* const* d_in, const int* in_sizes, int n_in,
                              void* d_out, int out_size, void* d_ws, size_t ws_size,
                              hipStream_t stream) {
    const int*   idx  = (const int*)d_in[0];    // topk_indices [B,N,K] int32
    const float* feat = (const float*)d_in[1];  // features [B,N,F] fp32
    float*       out  = (float*)d_out;          // [B,N,K,F] fp32

    gather_rows_kernel<<<GRID, BLOCK, 0, stream>>>(idx, feat, out);
}

// Round 11
// 186.425 us; speedup vs baseline: 7.9353x; 1.0997x over previous
//
#include <hip/hip_runtime.h>

// out[b, n, k, :] = features[b, topk_indices[b, n, k], :]
// B=32, N=4096, K=20, F=64, fp32.
//
// FINAL (best measured: 186.2 us). Ledger of structural variants:
//   naive grid-stride       187.1 us
//   XCD-affine (this)       186.2 us   <- best
//   nt stores               234 us     (L2 write-combining loss)
//   compiler unroll x4      208 us
//   1-deep SW pipeline      190 us
//   reg burst + barriers    376 us     (vmcnt drain + occupancy collapse)
//   8-deep wave batch       205 us
// Decomposition (R8): rd-only 62.5us/pass, wr-only ~90us/pass; mixed = 187
// = 1.23x serial sum, invariant across all interleave granularities.
// HBM-actual 4.4 TB/s (35% headroom): limit is mixed R/W service in L2/
// fabric, not HBM. Copy-footprint roofline (m13, 6.29 TB/s D2D) for our
// 1.34 GB logical footprint = 213 us; we beat it at 187 via cache-served
// reads. Declaring roofline.

constexpr int B = 32, N = 4096, K = 20, F = 64;
constexpr unsigned NK = (unsigned)N * K;                      // 81,920 rows/batch
constexpr unsigned F4_PER_FEAT_BATCH = (unsigned)N * F / 4;   // 65,536 float4
constexpr unsigned F4_PER_BATCH = NK * (F / 4);               // 1,310,720 float4 out/batch

constexpr unsigned BLOCK = 256;
constexpr unsigned CHUNKS_PER_BATCH = 256;                    // blocks per batch
constexpr unsigned GRID = (unsigned)B * CHUNKS_PER_BATCH;     // 8192 blocks
constexpr unsigned F4_PER_CHUNK = F4_PER_BATCH / CHUNKS_PER_BATCH;  // 5120
constexpr unsigned ITERS = F4_PER_CHUNK / BLOCK;              // 20
static_assert(ITERS * BLOCK * CHUNKS_PER_BATCH == F4_PER_BATCH, "exact tiling");

__global__ __launch_bounds__(BLOCK) void gather_rows_kernel(
    const int* __restrict__ idx,      // [B, N, K]
    const float* __restrict__ feat,   // [B, N, F]
    float* __restrict__ out)          // [B, N, K, F]
{
    // XCD-affine decomposition: xcd = blockIdx&7 (round-robin dispatch),
    // seq = temporal order within that XCD's block stream. XCD x handles
    // batches {x, x+8, x+16, x+24}, one batch phase at a time -> per-XCD
    // live feature slab ~1MB (L2-resident).
    const unsigned xcd = blockIdx.x & 7u;
    const unsigned seq = blockIdx.x >> 3;            // [0, 1024)
    const unsigned b   = xcd + 8u * (seq >> 8);      // batch [0,32): 4 per XCD, phased
    const unsigned c   = seq & 255u;                 // chunk within batch [0,256)

    const float4* __restrict__ featv = reinterpret_cast<const float4*>(feat);
    float4* __restrict__ outv = reinterpret_cast<float4*>(out);

    const int* __restrict__ idxb = idx + b * NK;
    const unsigned featbase = b * F4_PER_FEAT_BATCH;
    const unsigned outbase  = b * F4_PER_BATCH;

#pragma unroll 1
    for (unsigned j = 0; j < ITERS; ++j) {
        unsigned il  = c * F4_PER_CHUNK + j * BLOCK + threadIdx.x; // f4 idx within batch
        unsigned row = il >> 4;          // row within batch [0, N*K)
        unsigned v   = il & 15u;         // float4 slot within the 64-float row
        int id       = idxb[row];        // 16 lanes share this dword
        outv[outbase + il] = featv[featbase + ((unsigned)id << 4) + v];
    }
}

extern "C" void kernel_launch(void* const* d_in, const int* in_sizes, int n_in,
                              void* d_out, int out_size, void* d_ws, size_t ws_size,
                              hipStream_t stream) {
    const int*   idx  = (const int*)d_in[0];    // topk_indices [B,N,K] int32
    const float* feat = (const float*)d_in[1];  // features [B,N,F] fp32
    float*       out  = (float*)d_out;          // [B,N,K,F] fp32

    gather_rows_kernel<<<GRID, BLOCK, 0, stream>>>(idx, feat, out);
}